// Round 9
// baseline (734.514 us; speedup 1.0000x reference)
//
#include <hip/hip_runtime.h>

typedef __bf16 bf16_t;
typedef __bf16 bf16x4 __attribute__((ext_vector_type(4)));
typedef __bf16 bf16x8 __attribute__((ext_vector_type(8)));
typedef short s16x4 __attribute__((ext_vector_type(4)));
typedef float f32x4 __attribute__((ext_vector_type(4)));

#define BN_EPS 1e-3f

// ---------------- fp32 -> bf16 elementwise convert (8 elems/thread) ----------------
__global__ __launch_bounds__(256) void cvt_f32_bf16(
    const float* __restrict__ in, bf16_t* __restrict__ out, long n)
{
  long i = ((long)blockIdx.x * 256 + threadIdx.x) * 8;
  if (i + 8 > n) return;
  f32x4 a = *(const f32x4*)(in + i);
  f32x4 b = *(const f32x4*)(in + i + 4);
  bf16x8 o;
  o[0] = (bf16_t)a[0]; o[1] = (bf16_t)a[1]; o[2] = (bf16_t)a[2]; o[3] = (bf16_t)a[3];
  o[4] = (bf16_t)b[0]; o[5] = (bf16_t)b[1]; o[6] = (bf16_t)b[2]; o[7] = (bf16_t)b[3];
  *(bf16x8*)(out + i) = o;
}

// ---------------- weight transpose fp32 in[R][C] -> bf16 out[C][R] ----------------
__global__ __launch_bounds__(256) void transpose_f32_bf16(
    const float* __restrict__ in, bf16_t* __restrict__ out, int R, int C)
{
  __shared__ bf16_t t[32][33];
  int bx = blockIdx.x * 32, by = blockIdx.y * 32;
  int tx = threadIdx.x, ty = threadIdx.y;
#pragma unroll
  for (int i = 0; i < 32; i += 8)
    t[ty + i][tx] = (bf16_t)in[(long)(by + ty + i) * C + (bx + tx)];
  __syncthreads();
#pragma unroll
  for (int i = 0; i < 32; i += 8)
    out[(long)(bx + ty + i) * R + (by + tx)] = t[tx][ty + i];
}

// ------- Wkv split-transpose: fp32 [256][640] -> WkT[128][256], WvT[512][256] bf16 -------
__global__ __launch_bounds__(256) void wkv_split_transpose(
    const float* __restrict__ in, bf16_t* __restrict__ outK, bf16_t* __restrict__ outV)
{
  __shared__ bf16_t t[32][33];
  int bx = blockIdx.x * 32, by = blockIdx.y * 32;   // bx over 640 cols, by over 256 rows
  int tx = threadIdx.x, ty = threadIdx.y;
#pragma unroll
  for (int i = 0; i < 32; i += 8)
    t[ty + i][tx] = (bf16_t)in[(long)(by + ty + i) * 640 + (bx + tx)];
  __syncthreads();
#pragma unroll
  for (int i = 0; i < 32; i += 8) {
    int c = bx + ty + i;                 // kv channel 0..639
    int h = c / 80, r80 = c - h * 80;
    bf16_t v = t[tx][ty + i];
    if (r80 < 16)
      outK[(long)(h * 16 + r80) * 256 + (by + tx)] = v;
    else
      outV[(long)(h * 64 + (r80 - 16)) * 256 + (by + tx)] = v;
  }
}

// ---------------- fused GEMM + BN (+ scatter epilogues) ----------------
// MODE 0: K   A=xb[32768][256], WkT[128][256] -> K[bh][4096][16]
// MODE 1: Q   A=xb (strided row gather), WqT[128][256] -> Q[bh][1024][16] (*0.25*log2e)
// MODE 2: PROJ A=outp[8192][512], WpT[512][512] -> d_out fp32 [8192][512]
// MODE 3: V^T A=WvT[512][256], B=xb -> Vt[bh*64+dv][4096]  (coalesced Vt writes)
template <int MODE>
__global__ __launch_bounds__(256) void gemm_bn(
    const bf16_t* __restrict__ A, const bf16_t* __restrict__ Wt,
    const float* __restrict__ bias, const float* __restrict__ gamma,
    const float* __restrict__ beta, const float* __restrict__ mean,
    const float* __restrict__ var,
    bf16_t* __restrict__ out0, float* __restrict__ outf)
{
  constexpr int KTOT = (MODE == 2) ? 512 : 256;
  const int lane = threadIdx.x & 63;
  const int w = threadIdx.x >> 6;
  const int quad = lane >> 4, l15 = lane & 15;
  const int m0 = blockIdx.x * 64 + w * 16;
  const int n0 = blockIdx.y * 64;

  int mrow = m0 + l15;
  int arow;
  if constexpr (MODE == 1) {
    int b = mrow >> 10, qp = mrow & 1023;
    arow = (b << 12) + ((qp >> 5) << 7) + ((qp & 31) << 1);
  } else {
    arow = mrow;
  }
  const bf16_t* ap = A + (long)arow * KTOT + quad * 8;
  const bf16_t* bp = Wt + (long)(n0 + l15) * KTOT + quad * 8;

  f32x4 acc[4] = {};
#pragma unroll
  for (int ks = 0; ks < KTOT / 32; ks++) {
    bf16x8 a = *(const bf16x8*)(ap + ks * 32);
#pragma unroll
    for (int nt = 0; nt < 4; nt++) {
      bf16x8 bfr = *(const bf16x8*)(bp + (long)nt * 16 * KTOT + ks * 32);
      acc[nt] = __builtin_amdgcn_mfma_f32_16x16x32_bf16(a, bfr, acc[nt], 0, 0, 0);
    }
  }

  if constexpr (MODE == 3) {
    // rows = V channels, cols = x rows. BN per ROW.
    float sB[4], tB[4], bB[4];
#pragma unroll
    for (int r = 0; r < 4; r++) {
      int ch = m0 + quad * 4 + r;                      // 0..511
      int c = (ch >> 6) * 80 + 16 + (ch & 63);         // kv param index
      sB[r] = gamma[c] / sqrtf(var[c] + BN_EPS);
      tB[r] = beta[c] - mean[c] * sB[r];
      bB[r] = bias[c];
    }
#pragma unroll
    for (int nt = 0; nt < 4; nt++) {
      int n = n0 + nt * 16 + l15;                      // x row
      int b = n >> 12, seq = n & 4095;
#pragma unroll
      for (int r = 0; r < 4; r++) {
        int ch = m0 + quad * 4 + r;
        float y = (acc[nt][r] + bB[r]) * sB[r] + tB[r];
        out0[((long)((b * 8 + (ch >> 6)) * 64 + (ch & 63))) * 4096 + seq] = (bf16_t)y;
      }
    }
    return;
  }

#pragma unroll
  for (int nt = 0; nt < 4; nt++) {
    int col = n0 + nt * 16 + l15;
    int cp;
    if constexpr (MODE == 0) cp = (col >> 4) * 80 + (col & 15);
    else cp = col;
    float s = gamma[cp] / sqrtf(var[cp] + BN_EPS);
    float t = beta[cp] - mean[cp] * s;
    float bia = bias[cp];
#pragma unroll
    for (int r = 0; r < 4; r++) {
      int grow = m0 + quad * 4 + r;
      float y = (acc[nt][r] + bia) * s + t;
      if constexpr (MODE == 0) {
        int h = col >> 4, d = col & 15;
        int b = grow >> 12, seq = grow & 4095;
        out0[((long)((b * 8 + h) * 4096 + seq)) * 16 + d] = (bf16_t)y;   // K [bh][seq][16]
      } else if constexpr (MODE == 1) {
        int h = col >> 4, d = col & 15;
        int b = grow >> 10, qp = grow & 1023;
        out0[((long)((b * 8 + h) * 1024 + qp)) * 16 + d] = (bf16_t)(y * 0.36067376f);
      } else {
        outf[(long)grow * 512 + col] = y;
      }
    }
  }
}

// ---------------- flash attention, transpose-free + 4-deep register pipeline ----------------
// S^T = K·Q^T via mfma_16x16x16: C layout (key=quad*4+r, q=l15) == B-operand layout
// (k=quad*4+j, n=l15) of the PV MFMA O^T += V^T·P^T. exp2 in registers, NO LDS in loop.
// grid 4096: bh = blockIdx&63 (XCD locality), qt = blockIdx>>6 (64 q-tiles of 16 rows).
// 4 waves = 4-way key split (1024 keys each, 64 tiles of 16); LDS combine at end.
// 4-deep prefetch slots (kA[4], vA[4][4]) -> ~3 tiles of load-to-use cover, partial vmcnt.
__global__ __launch_bounds__(256, 4) void attn_kernel(
    const bf16_t* __restrict__ Q, const bf16_t* __restrict__ K,
    const bf16_t* __restrict__ Vt, bf16_t* __restrict__ outp)
{
  const int tid = threadIdx.x;
  const int lane = tid & 63, w = tid >> 6;       // w = key quarter 0..3
  const int quad = lane >> 4, l15 = lane & 15;
  const int bh = blockIdx.x & 63, qt = blockIdx.x >> 6;
  const int b = bh >> 3, h = bh & 7;
  const bf16_t* Qp = Q + (long)bh * 1024 * 16;
  const bf16_t* Kp = K + (long)bh * 4096 * 16;
  const bf16_t* Vp = Vt + (long)bh * 64 * 4096;

  __shared__ __align__(16) float comb[3 * 64 * 20];   // 15360 B

  const int q0 = qt * 16;
  // Q^T B-frag: lane(quad,l15) holds Q[q0+l15][d=quad*4..+3]
  s16x4 qB = *(const s16x4*)(Qp + (long)(q0 + l15) * 16 + quad * 4);

  f32x4 O[4] = {};           // O^T frags: lane holds (q=l15, dv=dt*16+quad*4+r)
  float lp = 0.f;            // per-lane partial key-sum for q=l15
  const f32x4 zf = {0.f, 0.f, 0.f, 0.f};

  const int kstart = w * 1024;
  const bf16_t* kpb = Kp + (long)(kstart + l15) * 16 + quad * 4;   // + t*256 elems
  const bf16_t* vpb = Vp + (long)l15 * 4096 + kstart + quad * 4;   // + dt*65536 + t*16

  s16x4 kA[4];
  s16x4 vA[4][4];
  auto loadT = [&](int i, int t) {
    kA[i] = *(const s16x4*)(kpb + (long)t * 256);
#pragma unroll
    for (int dt = 0; dt < 4; dt++)
      vA[i][dt] = *(const s16x4*)(vpb + (long)dt * 65536 + t * 16);
  };
  auto computeT = [&](int i) {
    f32x4 S = __builtin_amdgcn_mfma_f32_16x16x16bf16_1k(kA[i], qB, zf, 0, 0, 0);
    float p0 = exp2f(S[0]), p1 = exp2f(S[1]), p2 = exp2f(S[2]), p3 = exp2f(S[3]);
    lp += (p0 + p1) + (p2 + p3);
    bf16x4 pk; pk[0] = (bf16_t)p0; pk[1] = (bf16_t)p1; pk[2] = (bf16_t)p2; pk[3] = (bf16_t)p3;
    s16x4 pB = __builtin_bit_cast(s16x4, pk);
#pragma unroll
    for (int dt = 0; dt < 4; dt++)
      O[dt] = __builtin_amdgcn_mfma_f32_16x16x16bf16_1k(vA[i][dt], pB, O[dt], 0, 0, 0);
  };

  // prime 4 slots, then steady-state: compute slot i, immediately refill with tile kt+4+i.
  // Tail loads (tiles 64..67) overread into adjacent ws buffers (in-bounds, values unused).
#pragma unroll
  for (int i = 0; i < 4; i++) loadT(i, i);
  for (int kt = 0; kt < 64; kt += 4) {
#pragma unroll
    for (int i = 0; i < 4; i++) {
      computeT(i);
      loadT(i, kt + 4 + i);
    }
  }

  // reduce lp over quads: all lanes with same l15 get this wave's key-sum
  lp += __shfl_xor(lp, 16);
  lp += __shfl_xor(lp, 32);

  // ------- combine 4 key-quarters -------
  __syncthreads();
  if (w != 0) {
    float* dst = comb + ((w - 1) * 64 + lane) * 20;
#pragma unroll
    for (int dt = 0; dt < 4; dt++)
      *(f32x4*)(dst + dt * 4) = O[dt];
    dst[16] = lp;
  }
  __syncthreads();
  if (w == 0) {
#pragma unroll
    for (int j = 0; j < 3; j++) {
      const float* src = comb + (j * 64 + lane) * 20;
#pragma unroll
      for (int dt = 0; dt < 4; dt++)
        O[dt] += *(const f32x4*)(src + dt * 4);
      lp += src[16];
    }
    float rl = 1.f / lp;
    int q = q0 + l15;
    long colq = q & 511;
    long rowbase = (long)b * 1024 + (long)h * 128 + (q >> 9);
#pragma unroll
    for (int dt = 0; dt < 4; dt++) {
#pragma unroll
      for (int r = 0; r < 4; r++) {
        int dv = dt * 16 + quad * 4 + r;
        float val = O[dt][r] * rl;
        float hs = val * fminf(fmaxf(val + 3.f, 0.f), 6.f) * (1.f / 6.f);
        outp[(rowbase + (long)dv * 2) * 512 + colq] = (bf16_t)hs;
      }
    }
  }
}

extern "C" void kernel_launch(void* const* d_in, const int* in_sizes, int n_in,
                              void* d_out, int out_size, void* d_ws, size_t ws_size,
                              hipStream_t stream)
{
  const float* x    = (const float*)d_in[0];
  const float* Wkv  = (const float*)d_in[1];
  const float* bkv  = (const float*)d_in[2];
  const float* g_kv = (const float*)d_in[3];
  const float* b_kv = (const float*)d_in[4];
  const float* m_kv = (const float*)d_in[5];
  const float* v_kv = (const float*)d_in[6];
  const float* Wq   = (const float*)d_in[7];
  const float* bq   = (const float*)d_in[8];
  const float* g_q  = (const float*)d_in[9];
  const float* b_q  = (const float*)d_in[10];
  const float* m_q  = (const float*)d_in[11];
  const float* v_q  = (const float*)d_in[12];
  const float* Wp   = (const float*)d_in[13];
  const float* bp   = (const float*)d_in[14];
  const float* g_p  = (const float*)d_in[15];
  const float* b_p  = (const float*)d_in[16];
  const float* m_p  = (const float*)d_in[17];
  const float* v_p  = (const float*)d_in[18];

  char* ws = (char*)d_ws;
  bf16_t* xb   = (bf16_t*)ws; ws += (long)8 * 4096 * 256 * 2;
  bf16_t* WkT  = (bf16_t*)ws; ws += (long)128 * 256 * 2;
  bf16_t* WvT  = (bf16_t*)ws; ws += (long)512 * 256 * 2;
  bf16_t* Wq_t = (bf16_t*)ws; ws += (long)128 * 256 * 2;
  bf16_t* Wp_t = (bf16_t*)ws; ws += (long)512 * 512 * 2;
  bf16_t* Qbuf = (bf16_t*)ws; ws += (long)64 * 1024 * 16 * 2;
  bf16_t* Kbuf = (bf16_t*)ws; ws += (long)64 * 4096 * 16 * 2;
  bf16_t* Vtb  = (bf16_t*)ws; ws += (long)64 * 64 * 4096 * 2;
  bf16_t* outp = (bf16_t*)ws; ws += (long)8192 * 512 * 2;
  ws += 16384;  // slack for attention tail-prefetch overread past Vtb/outp

  cvt_f32_bf16<<<dim3(4096), 256, 0, stream>>>(x, xb, (long)8 * 4096 * 256);

  wkv_split_transpose<<<dim3(20, 8), dim3(32, 8), 0, stream>>>(Wkv, WkT, WvT);
  transpose_f32_bf16<<<dim3(4, 8),   dim3(32, 8), 0, stream>>>(Wq, Wq_t, 256, 128);
  transpose_f32_bf16<<<dim3(16, 16), dim3(32, 8), 0, stream>>>(Wp, Wp_t, 512, 512);

  gemm_bn<0><<<dim3(512, 2), 256, 0, stream>>>(xb, WkT, bkv, g_kv, b_kv, m_kv, v_kv, Kbuf, nullptr);
  gemm_bn<3><<<dim3(8, 512), 256, 0, stream>>>(WvT, xb, bkv, g_kv, b_kv, m_kv, v_kv, Vtb, nullptr);
  gemm_bn<1><<<dim3(128, 2), 256, 0, stream>>>(xb, Wq_t, bq, g_q, b_q, m_q, v_q, Qbuf, nullptr);

  attn_kernel<<<dim3(4096), 256, 0, stream>>>(Qbuf, Kbuf, Vtb, outp);

  gemm_bn<2><<<dim3(128, 8), 256, 0, stream>>>(outp, Wp_t, bp, g_p, b_p, m_p, v_p, nullptr, (float*)d_out);
}

// Round 10
// 374.483 us; speedup vs baseline: 1.9614x; 1.9614x over previous
//
#include <hip/hip_runtime.h>

typedef __bf16 bf16_t;
typedef __bf16 bf16x4 __attribute__((ext_vector_type(4)));
typedef __bf16 bf16x8 __attribute__((ext_vector_type(8)));
typedef short s16x4 __attribute__((ext_vector_type(4)));
typedef float f32x4 __attribute__((ext_vector_type(4)));

#define BN_EPS 1e-3f

#define GLOAD_LDS16(g, l) \
  __builtin_amdgcn_global_load_lds((const __attribute__((address_space(1))) void*)(g), \
                                   (__attribute__((address_space(3))) void*)(l), 16, 0, 0)

// ---------------- fp32 -> bf16 elementwise convert (8 elems/thread) ----------------
__global__ __launch_bounds__(256) void cvt_f32_bf16(
    const float* __restrict__ in, bf16_t* __restrict__ out, long n)
{
  long i = ((long)blockIdx.x * 256 + threadIdx.x) * 8;
  if (i + 8 > n) return;
  f32x4 a = *(const f32x4*)(in + i);
  f32x4 b = *(const f32x4*)(in + i + 4);
  bf16x8 o;
  o[0] = (bf16_t)a[0]; o[1] = (bf16_t)a[1]; o[2] = (bf16_t)a[2]; o[3] = (bf16_t)a[3];
  o[4] = (bf16_t)b[0]; o[5] = (bf16_t)b[1]; o[6] = (bf16_t)b[2]; o[7] = (bf16_t)b[3];
  *(bf16x8*)(out + i) = o;
}

// ---------------- weight transpose fp32 in[R][C] -> bf16 out[C][R] ----------------
__global__ __launch_bounds__(256) void transpose_f32_bf16(
    const float* __restrict__ in, bf16_t* __restrict__ out, int R, int C)
{
  __shared__ bf16_t t[32][33];
  int bx = blockIdx.x * 32, by = blockIdx.y * 32;
  int tx = threadIdx.x, ty = threadIdx.y;
#pragma unroll
  for (int i = 0; i < 32; i += 8)
    t[ty + i][tx] = (bf16_t)in[(long)(by + ty + i) * C + (bx + tx)];
  __syncthreads();
#pragma unroll
  for (int i = 0; i < 32; i += 8)
    out[(long)(bx + ty + i) * R + (by + tx)] = t[tx][ty + i];
}

// ------- Wkv split-transpose: fp32 [256][640] -> WkT[128][256], WvT[512][256] bf16 -------
__global__ __launch_bounds__(256) void wkv_split_transpose(
    const float* __restrict__ in, bf16_t* __restrict__ outK, bf16_t* __restrict__ outV)
{
  __shared__ bf16_t t[32][33];
  int bx = blockIdx.x * 32, by = blockIdx.y * 32;   // bx over 640 cols, by over 256 rows
  int tx = threadIdx.x, ty = threadIdx.y;
#pragma unroll
  for (int i = 0; i < 32; i += 8)
    t[ty + i][tx] = (bf16_t)in[(long)(by + ty + i) * 640 + (bx + tx)];
  __syncthreads();
#pragma unroll
  for (int i = 0; i < 32; i += 8) {
    int c = bx + ty + i;                 // kv channel 0..639
    int h = c / 80, r80 = c - h * 80;
    bf16_t v = t[tx][ty + i];
    if (r80 < 16)
      outK[(long)(h * 16 + r80) * 256 + (by + tx)] = v;
    else
      outV[(long)(h * 64 + (r80 - 16)) * 256 + (by + tx)] = v;
  }
}

// ---------------- fused GEMM + BN (+ scatter epilogues) ----------------
// MODE 0: K   A=xb[32768][256], WkT[128][256] -> K[bh][4096][16]
// MODE 1: Q   A=xb (strided row gather), WqT[128][256] -> Q[bh][1024][16] (*0.25*log2e)
// MODE 2: PROJ A=outp[8192][512], WpT[512][512] -> d_out fp32 [8192][512]
// MODE 3: V^T A=WvT[512][256], B=xb -> Vt[bh*64+dv][4096]  (coalesced Vt writes)
template <int MODE>
__global__ __launch_bounds__(256) void gemm_bn(
    const bf16_t* __restrict__ A, const bf16_t* __restrict__ Wt,
    const float* __restrict__ bias, const float* __restrict__ gamma,
    const float* __restrict__ beta, const float* __restrict__ mean,
    const float* __restrict__ var,
    bf16_t* __restrict__ out0, float* __restrict__ outf)
{
  constexpr int KTOT = (MODE == 2) ? 512 : 256;
  const int lane = threadIdx.x & 63;
  const int w = threadIdx.x >> 6;
  const int quad = lane >> 4, l15 = lane & 15;
  const int m0 = blockIdx.x * 64 + w * 16;
  const int n0 = blockIdx.y * 64;

  int mrow = m0 + l15;
  int arow;
  if constexpr (MODE == 1) {
    int b = mrow >> 10, qp = mrow & 1023;
    arow = (b << 12) + ((qp >> 5) << 7) + ((qp & 31) << 1);
  } else {
    arow = mrow;
  }
  const bf16_t* ap = A + (long)arow * KTOT + quad * 8;
  const bf16_t* bp = Wt + (long)(n0 + l15) * KTOT + quad * 8;

  f32x4 acc[4] = {};
#pragma unroll
  for (int ks = 0; ks < KTOT / 32; ks++) {
    bf16x8 a = *(const bf16x8*)(ap + ks * 32);
#pragma unroll
    for (int nt = 0; nt < 4; nt++) {
      bf16x8 bfr = *(const bf16x8*)(bp + (long)nt * 16 * KTOT + ks * 32);
      acc[nt] = __builtin_amdgcn_mfma_f32_16x16x32_bf16(a, bfr, acc[nt], 0, 0, 0);
    }
  }

  if constexpr (MODE == 3) {
    // rows = V channels, cols = x rows. BN per ROW.
    float sB[4], tB[4], bB[4];
#pragma unroll
    for (int r = 0; r < 4; r++) {
      int ch = m0 + quad * 4 + r;                      // 0..511
      int c = (ch >> 6) * 80 + 16 + (ch & 63);         // kv param index
      sB[r] = gamma[c] / sqrtf(var[c] + BN_EPS);
      tB[r] = beta[c] - mean[c] * sB[r];
      bB[r] = bias[c];
    }
#pragma unroll
    for (int nt = 0; nt < 4; nt++) {
      int n = n0 + nt * 16 + l15;                      // x row
      int b = n >> 12, seq = n & 4095;
#pragma unroll
      for (int r = 0; r < 4; r++) {
        int ch = m0 + quad * 4 + r;
        float y = (acc[nt][r] + bB[r]) * sB[r] + tB[r];
        out0[((long)((b * 8 + (ch >> 6)) * 64 + (ch & 63))) * 4096 + seq] = (bf16_t)y;
      }
    }
    return;
  }

#pragma unroll
  for (int nt = 0; nt < 4; nt++) {
    int col = n0 + nt * 16 + l15;
    int cp;
    if constexpr (MODE == 0) cp = (col >> 4) * 80 + (col & 15);
    else cp = col;
    float s = gamma[cp] / sqrtf(var[cp] + BN_EPS);
    float t = beta[cp] - mean[cp] * s;
    float bia = bias[cp];
#pragma unroll
    for (int r = 0; r < 4; r++) {
      int grow = m0 + quad * 4 + r;
      float y = (acc[nt][r] + bia) * s + t;
      if constexpr (MODE == 0) {
        int h = col >> 4, d = col & 15;
        int b = grow >> 12, seq = grow & 4095;
        out0[((long)((b * 8 + h) * 4096 + seq)) * 16 + d] = (bf16_t)y;   // K [bh][seq][16]
      } else if constexpr (MODE == 1) {
        int h = col >> 4, d = col & 15;
        int b = grow >> 10, qp = grow & 1023;
        out0[((long)((b * 8 + h) * 1024 + qp)) * 16 + d] = (bf16_t)(y * 0.36067376f);
      } else {
        outf[(long)grow * 512 + col] = y;
      }
    }
  }
}

// ---------------- flash attention: LDS double-buffered K/V DMA + transpose-free MFMA ----------------
// Block = 512 thr (8 waves), each wave owns 16 q rows (128 q rows/block); ALL 4096 keys
// looped in 64-key tiles -> no split-K combine. Grid 512 = 64 bh x 8 qb (2 blocks/CU,
// all co-resident; bh = blockIdx&63 pins same-bh blocks to one XCD for L2 K/V reuse).
// Staging: __builtin_amdgcn_global_load_lds width=16 (async DMA, no VGPR round-trip),
// double-buffered; one __syncthreads per tile (implicit vmcnt drain = the only wait).
// Math (verified R8/R9): S^T = K·Q^T via mfma_16x16x16bf16; exp'd C-frag IS the PV
// B-frag (O^T += V^T·P^T). exp2 softmax, scale folded into Q.
__global__ __launch_bounds__(512, 4) void attn_kernel(
    const bf16_t* __restrict__ Q, const bf16_t* __restrict__ K,
    const bf16_t* __restrict__ Vt, bf16_t* __restrict__ outp)
{
  const int tid = threadIdx.x;
  const int lane = tid & 63, w = tid >> 6;       // 8 waves
  const int quad = lane >> 4, l15 = lane & 15;
  const int bh = blockIdx.x & 63, qb = blockIdx.x >> 6;
  const int b = bh >> 3, h = bh & 7;
  const bf16_t* Qp = Q + (long)bh * 1024 * 16;
  const char* Kg = (const char*)(K + (long)bh * 4096 * 16);    // [key][16d], 32 B/row
  const char* Vg = (const char*)(Vt + (long)bh * 64 * 4096);   // [dv][4096], 8192 B/row

  // K tile: [64 keys][16 d] = 2048 B (straight copy of global chunk)
  // V tile: [key8 g][dv][8 keys] = 8 groups x 64 dv x 16 B = 8192 B
  __shared__ __align__(16) char Kl[2][2048];
  __shared__ __align__(16) char Vl[2][8192];

  const int q0 = qb * 128 + w * 16;
  // Q^T B-frag: lane(quad,l15) holds Q[q0+l15][d=quad*4..+3]
  s16x4 qB = *(const s16x4*)(Qp + (long)(q0 + l15) * 16 + quad * 4);

  f32x4 O[4] = {};           // O^T frags: lane holds (q=l15, dv=dt*16+quad*4+r)
  float lp = 0.f;
  const f32x4 zf = {0.f, 0.f, 0.f, 0.f};

  auto stage = [&](int t, int buf) {
    // V chunk: wave w stages key8-group g=w: lane=dv, 16 B = keys [t*64+w*8, +8)
    GLOAD_LDS16(Vg + (long)lane * 8192 + (long)t * 128 + w * 16, &Vl[buf][w * 1024]);
    // K: 2 KB contiguous; waves 0,1 stage 1 KB each (lane*16 straight copy)
    if (w < 2)
      GLOAD_LDS16(Kg + (long)t * 2048 + w * 1024 + (long)lane * 16, &Kl[buf][w * 1024]);
  };

  auto compute = [&](int buf) {
#pragma unroll
    for (int st = 0; st < 4; st++) {
      const int k0 = st * 16;
      s16x4 kA = *(const s16x4*)(&Kl[buf][(k0 + l15) * 32 + quad * 8]);
      f32x4 S = __builtin_amdgcn_mfma_f32_16x16x16bf16_1k(kA, qB, zf, 0, 0, 0);
      float p0 = exp2f(S[0]), p1 = exp2f(S[1]), p2 = exp2f(S[2]), p3 = exp2f(S[3]);
      lp += (p0 + p1) + (p2 + p3);
      bf16x4 pk; pk[0] = (bf16_t)p0; pk[1] = (bf16_t)p1; pk[2] = (bf16_t)p2; pk[3] = (bf16_t)p3;
      s16x4 pB = __builtin_bit_cast(s16x4, pk);
      // V read: lane needs V[dv=dt*16+l15][keys k0+quad*4..+3] (8 B)
      const int vbase = (k0 >> 3) * 1024 + (quad >> 1) * 1024 + (quad & 1) * 8;
#pragma unroll
      for (int dt = 0; dt < 4; dt++) {
        s16x4 vA = *(const s16x4*)(&Vl[buf][vbase + (dt * 16 + l15) * 16]);
        O[dt] = __builtin_amdgcn_mfma_f32_16x16x16bf16_1k(vA, pB, O[dt], 0, 0, 0);
      }
    }
  };

  stage(0, 0);
  for (int t = 0; t < 64; t++) {
    __syncthreads();                    // drains staging of tile t; fences buffer reuse
    if (t < 63) stage(t + 1, (t + 1) & 1);
    compute(t & 1);
  }

  // reduce lp over quads: all lanes with same l15 get the full key-sum
  lp += __shfl_xor(lp, 16);
  lp += __shfl_xor(lp, 32);
  float rl = 1.f / lp;

  int q = q0 + l15;
  long colq = q & 511;
  long rowbase = (long)b * 1024 + (long)h * 128 + (q >> 9);
#pragma unroll
  for (int dt = 0; dt < 4; dt++) {
#pragma unroll
    for (int r = 0; r < 4; r++) {
      int dv = dt * 16 + quad * 4 + r;
      float val = O[dt][r] * rl;
      float hs = val * fminf(fmaxf(val + 3.f, 0.f), 6.f) * (1.f / 6.f);
      outp[(rowbase + (long)dv * 2) * 512 + colq] = (bf16_t)hs;
    }
  }
}

extern "C" void kernel_launch(void* const* d_in, const int* in_sizes, int n_in,
                              void* d_out, int out_size, void* d_ws, size_t ws_size,
                              hipStream_t stream)
{
  const float* x    = (const float*)d_in[0];
  const float* Wkv  = (const float*)d_in[1];
  const float* bkv  = (const float*)d_in[2];
  const float* g_kv = (const float*)d_in[3];
  const float* b_kv = (const float*)d_in[4];
  const float* m_kv = (const float*)d_in[5];
  const float* v_kv = (const float*)d_in[6];
  const float* Wq   = (const float*)d_in[7];
  const float* bq   = (const float*)d_in[8];
  const float* g_q  = (const float*)d_in[9];
  const float* b_q  = (const float*)d_in[10];
  const float* m_q  = (const float*)d_in[11];
  const float* v_q  = (const float*)d_in[12];
  const float* Wp   = (const float*)d_in[13];
  const float* bp   = (const float*)d_in[14];
  const float* g_p  = (const float*)d_in[15];
  const float* b_p  = (const float*)d_in[16];
  const float* m_p  = (const float*)d_in[17];
  const float* v_p  = (const float*)d_in[18];

  char* ws = (char*)d_ws;
  bf16_t* xb   = (bf16_t*)ws; ws += (long)8 * 4096 * 256 * 2;
  bf16_t* WkT  = (bf16_t*)ws; ws += (long)128 * 256 * 2;
  bf16_t* WvT  = (bf16_t*)ws; ws += (long)512 * 256 * 2;
  bf16_t* Wq_t = (bf16_t*)ws; ws += (long)128 * 256 * 2;
  bf16_t* Wp_t = (bf16_t*)ws; ws += (long)512 * 512 * 2;
  bf16_t* Qbuf = (bf16_t*)ws; ws += (long)64 * 1024 * 16 * 2;
  bf16_t* Kbuf = (bf16_t*)ws; ws += (long)64 * 4096 * 16 * 2;
  bf16_t* Vtb  = (bf16_t*)ws; ws += (long)64 * 64 * 4096 * 2;
  bf16_t* outp = (bf16_t*)ws; ws += (long)8192 * 512 * 2;
  ws += 16384;  // slack

  cvt_f32_bf16<<<dim3(4096), 256, 0, stream>>>(x, xb, (long)8 * 4096 * 256);

  wkv_split_transpose<<<dim3(20, 8), dim3(32, 8), 0, stream>>>(Wkv, WkT, WvT);
  transpose_f32_bf16<<<dim3(4, 8),   dim3(32, 8), 0, stream>>>(Wq, Wq_t, 256, 128);
  transpose_f32_bf16<<<dim3(16, 16), dim3(32, 8), 0, stream>>>(Wp, Wp_t, 512, 512);

  gemm_bn<0><<<dim3(512, 2), 256, 0, stream>>>(xb, WkT, bkv, g_kv, b_kv, m_kv, v_kv, Kbuf, nullptr);
  gemm_bn<3><<<dim3(8, 512), 256, 0, stream>>>(WvT, xb, bkv, g_kv, b_kv, m_kv, v_kv, Vtb, nullptr);
  gemm_bn<1><<<dim3(128, 2), 256, 0, stream>>>(xb, Wq_t, bq, g_q, b_q, m_q, v_q, Qbuf, nullptr);

  attn_kernel<<<dim3(512), 512, 0, stream>>>(Qbuf, Kbuf, Vtb, outp);

  gemm_bn<2><<<dim3(128, 8), 256, 0, stream>>>(outp, Wp_t, bp, g_p, b_p, m_p, v_p, nullptr, (float*)d_out);
}